// Round 16
// baseline (203.461 us; speedup 1.0000x reference)
//
#include <hip/hip_runtime.h>
#include <math.h>

#define B_PAIRS 4096
#define NNODES  64
#define NEDGES  256
#define FDIM    128
#define HDIM    64
#define FPDIM   2048
#define MDIM    256
#define KTOT    4224   // 2*HDIM + 2*FPDIM
#define SLICE   8704   // per-wave LDS slice: cnt/temp 8448 + nrm 256

typedef __attribute__((ext_vector_type(4))) float f32x4;
typedef __bf16 bf16x8 __attribute__((ext_vector_type(8)));

__device__ __forceinline__ unsigned short f2bf(float f) {
    return __builtin_bit_cast(unsigned short, (__bf16)f);
}
__device__ __forceinline__ unsigned pack2(float a, float b) {
    return (unsigned)f2bf(a) | ((unsigned)f2bf(b) << 16);
}
__device__ __forceinline__ unsigned long long pack4(float a, float b, float c, float d) {
    return (unsigned long long)pack2(a, b) | ((unsigned long long)pack2(c, d) << 32);
}
__device__ __forceinline__ bf16x8 cvt8(float4 u, float4 v) {
    bf16x8 a;
    a[0] = (__bf16)u.x; a[1] = (__bf16)u.y; a[2] = (__bf16)u.z; a[3] = (__bf16)u.w;
    a[4] = (__bf16)v.x; a[5] = (__bf16)v.y; a[6] = (__bf16)v.z; a[7] = (__bf16)v.w;
    return a;
}

// ---------------------------------------------------------------------------
// Kernel 0a: W1t[n][k]=W1[k][n], W2t[n][k]=W2[k][n] (bf16), grid-strided.
// ---------------------------------------------------------------------------
__global__ void prep_weights(const float* __restrict__ W1, const float* __restrict__ W2,
                             unsigned short* __restrict__ W1t, unsigned short* __restrict__ W2t) {
    const int t0 = blockIdx.x * 256 + threadIdx.x;
    const int stride = gridDim.x * 256;
    for (int i = t0; i < HDIM * FDIM; i += stride) {
        const int n = i >> 7, k = i & 127;
        W1t[i] = f2bf(W1[k * HDIM + n]);
    }
    for (int i = t0; i < HDIM * HDIM; i += stride) {
        const int n = i >> 6, k = i & 63;
        W2t[i] = f2bf(W2[k * HDIM + n]);
    }
}

// ---------------------------------------------------------------------------
// Kernel 0b: Wm1t[n][k] = bf16(Wm1[k][n]), n<256, k<4224. Tiled 32x32 via LDS.
// ---------------------------------------------------------------------------
__global__ __launch_bounds__(256)
void prep_wm1(const float* __restrict__ Wm1, unsigned short* __restrict__ Wm1t) {
    __shared__ float tile[32][33];
    const int k0 = blockIdx.x * 32, n0 = blockIdx.y * 32;
    const int t = threadIdx.x;
    const int c = t & 31, r8 = t >> 5;
    #pragma unroll
    for (int rr = r8; rr < 32; rr += 8)
        tile[rr][c] = Wm1[(size_t)(k0 + rr) * MDIM + n0 + c];
    __syncthreads();
    #pragma unroll
    for (int j = 0; j < 4; ++j) {
        const int n = n0 + r8 + 8 * j;
        Wm1t[(size_t)n * KTOT + k0 + c] = f2bf(tile[c][r8 + 8 * j]);
    }
}

#define WAITLDS() do { __asm__ volatile("s_waitcnt lgkmcnt(0)" ::: "memory"); \
                       __builtin_amdgcn_sched_barrier(0); } while (0)

// ---------------------------------------------------------------------------
// Kernel 1: per-graph GCN encoder — 4 INDEPENDENT waves per 256-thread block
// (one graph per wave, zero __syncthreads; private 8704-B LDS slice per wave).
// R16: R15's quarter-streamed body (true peak ~105 total regs) + forced
// __launch_bounds__(256,4) to land in the 128-total-reg bin (R11 proved the
// bin gives 16 waves/CU -> 3 TB/s; R15 proved the body fits w/o that bound's
// old spill source: only 8 float4 of x live at once).
// Per-slice layout:
//   [   0, 8448)  cnt u32[64][33] (early); temp bf16 8K [0,8192) after
//   [8448, 8704)  nrm[64]
// ---------------------------------------------------------------------------
__global__ __launch_bounds__(256, 4)
void encode_kernel(const float* __restrict__ x1, const float* __restrict__ x2,
                   const int* __restrict__ e1, const int* __restrict__ e2,
                   const unsigned short* __restrict__ W1t, const float* __restrict__ b1,
                   const unsigned short* __restrict__ W2t, const float* __restrict__ b2,
                   float* __restrict__ hbuf) {
    __shared__ __align__(16) unsigned char lds[4 * SLICE];
    const int wid = threadIdx.x >> 6;             // wave 0..3 = graph slot
    const int t   = threadIdx.x & 63;             // lane 0..63
    const int gid  = blockIdx.x * 4 + wid;        // 0..8191 = one graph
    const int drug = gid >> 12;
    const int b    = gid & (B_PAIRS - 1);
    const float* x  = (drug ? x2 : x1) + (size_t)b * NNODES * FDIM;
    const int*   eg = (drug ? e2 : e1) + (size_t)b * 2 * NEDGES;

    const int lr = t & 15, lg = t >> 4;
    const unsigned swl = (unsigned)(lr & 7) << 4; // row swizzle (rows ≡ lr mod 8)

    unsigned char* sl = lds + wid * SLICE;        // this wave's private slice
    unsigned* cnt = (unsigned*)sl;                // u32[64][33]
    float*    nrm = (float*)(sl + 8448);

    // ---- fire quarter-0 x loads (8 float4 = 32 VGPR, the ONLY x buffer) ----
    float4 xq[8];
    {
        const float* xr = x + (size_t)lr * FDIM + 8 * lg;
        #pragma unroll
        for (int ks = 0; ks < 4; ++ks) {
            xq[2 * ks]     = ((const float4*)(xr + 32 * ks))[0];
            xq[2 * ks + 1] = ((const float4*)(xr + 32 * ks))[1];
        }
    }
    // edges straight to registers (4 edges/lane)
    const int4 s4 = ((const int4*)eg)[t];
    const int4 d4 = ((const int4*)eg)[t + 64];

    // ---- zero cnt (2112 u32) ----
    #pragma unroll
    for (int i = 0; i < 8; ++i) ((uint4*)cnt)[t + 64 * i] = make_uint4(0, 0, 0, 0);
    cnt[2048 + t] = 0;
    WAITLDS();

    // ---- multiplicity atomics only (deg derived from cnt) ----
    {
        const int ss[4] = {s4.x, s4.y, s4.z, s4.w};
        const int dd[4] = {d4.x, d4.y, d4.z, d4.w};
        #pragma unroll
        for (int i = 0; i < 4; ++i)
            atomicAdd(&cnt[dd[i] * 33 + (ss[i] >> 1)], 1u << ((ss[i] & 1) * 16));
    }
    WAITLDS();

    // ---- deg[t] = row-sum of cnt row t; nrm = rsqrt(deg+1) ----
    {
        unsigned ssum = 0;
        #pragma unroll
        for (int j = 0; j < 33; ++j) {
            const unsigned w = cnt[t * 33 + j];
            ssum += (w & 0xffffu) + (w >> 16);
        }
        nrm[t] = rsqrtf((float)ssum + 1.0f);
    }
    WAITLDS();

    // ---- build A-hat FRAGMENTS in registers ----
    // frag(q,ks): rows 16q+lr, cols 32ks+8lg+e. Serves BOTH step2's B-operand
    // and step4's A-operand (identical lane mapping).
    bf16x8 ahat[8];
    {
        const float ncol[2][8] = {
            { nrm[8 * lg + 0], nrm[8 * lg + 1], nrm[8 * lg + 2], nrm[8 * lg + 3],
              nrm[8 * lg + 4], nrm[8 * lg + 5], nrm[8 * lg + 6], nrm[8 * lg + 7] },
            { nrm[32 + 8 * lg + 0], nrm[32 + 8 * lg + 1], nrm[32 + 8 * lg + 2], nrm[32 + 8 * lg + 3],
              nrm[32 + 8 * lg + 4], nrm[32 + 8 * lg + 5], nrm[32 + 8 * lg + 6], nrm[32 + 8 * lg + 7] }
        };
        #pragma unroll
        for (int q = 0; q < 4; ++q) {
            const int r = 16 * q + lr;
            const float nr = nrm[r];
            #pragma unroll
            for (int ks = 0; ks < 2; ++ks) {
                const int c0 = 32 * ks + 8 * lg;          // even, /2 -> word idx
                const uint4 w = *(const uint4*)(cnt + r * 33 + (c0 >> 1));
                const unsigned ww[4] = { w.x, w.y, w.z, w.w };
                bf16x8 f;
                #pragma unroll
                for (int e = 0; e < 8; ++e) {
                    const int c = c0 + e;
                    const unsigned m = (e & 1) ? (ww[e >> 1] >> 16) : (ww[e >> 1] & 0xffffu);
                    const float v = (float)(m + (r == c ? 1u : 0u)) * nr * ncol[ks][e];
                    f[e] = (__bf16)v;
                }
                ahat[q * 2 + ks] = f;
            }
        }
    }
    WAITLDS();                                    // all cnt reads retired; temp free

    // ---- step1: T1 = X @ W1, QUARTER-STREAMED (one mt row-block at a time).
    // Single x buffer; next quarter's loads issued right after conversion.
    // 2-pass over nt keeps only 8 W1t fragments (16 VGPR) live.
    #pragma unroll 1
    for (int q = 0; q < 4; ++q) {
        bf16x8 af[4];
        #pragma unroll
        for (int ks = 0; ks < 4; ++ks) af[ks] = cvt8(xq[2 * ks], xq[2 * ks + 1]);
        if (q < 3) {                              // refill buffer for quarter q+1
            const float* xr = x + (size_t)(16 * (q + 1) + lr) * FDIM + 8 * lg;
            #pragma unroll
            for (int ks = 0; ks < 4; ++ks) {
                xq[2 * ks]     = ((const float4*)(xr + 32 * ks))[0];
                xq[2 * ks + 1] = ((const float4*)(xr + 32 * ks))[1];
            }
        }
        f32x4 acc[4];
        #pragma unroll
        for (int nt = 0; nt < 4; ++nt) acc[nt] = (f32x4){0.f, 0.f, 0.f, 0.f};
        #pragma unroll
        for (int pass = 0; pass < 2; ++pass) {
            bf16x8 bw[8];
            #pragma unroll
            for (int j = 0; j < 2; ++j)
                #pragma unroll
                for (int ks = 0; ks < 4; ++ks)
                    bw[j * 4 + ks] = *(const bf16x8*)(W1t + (16 * (2 * pass + j) + lr) * FDIM + 32 * ks + 8 * lg);
            #pragma unroll
            for (int ks = 0; ks < 4; ++ks)
                #pragma unroll
                for (int j = 0; j < 2; ++j)
                    acc[2 * pass + j] = __builtin_amdgcn_mfma_f32_16x16x32_bf16(af[ks], bw[j * 4 + ks], acc[2 * pass + j], 0, 0, 0);
        }
        const unsigned m2 = (unsigned)(2 * (16 * q + 4 * lg));
        #pragma unroll
        for (int nt = 0; nt < 4; ++nt) {
            const int f = 16 * nt + lr;
            *(unsigned long long*)(sl + (unsigned)f * 128 + (m2 ^ swl)) =
                pack4(acc[nt][0], acc[nt][1], acc[nt][2], acc[nt][3]);
        }
    }
    WAITLDS();                                    // T1t visible

    // ---- step2: T2^T = T1t @ A^T (+b1, relu) -> T2b OVER temp ----
    {
        bf16x8 ta[8];
        #pragma unroll
        for (int mt = 0; mt < 4; ++mt)
            #pragma unroll
            for (int ks = 0; ks < 2; ++ks)
                ta[mt * 2 + ks] = *(const bf16x8*)(sl + (unsigned)(16 * mt + lr) * 128 +
                                                   (((unsigned)(64 * ks + 16 * lg)) ^ swl));
        WAITLDS();                                // reads done before overwrite
        #pragma unroll
        for (int mt = 0; mt < 4; ++mt) {
            f32x4 acc[4];
            #pragma unroll
            for (int nt = 0; nt < 4; ++nt) acc[nt] = (f32x4){0.f, 0.f, 0.f, 0.f};
            #pragma unroll
            for (int ks = 0; ks < 2; ++ks)
                #pragma unroll
                for (int nt = 0; nt < 4; ++nt)
                    acc[nt] = __builtin_amdgcn_mfma_f32_16x16x32_bf16(ta[mt * 2 + ks], ahat[nt * 2 + ks], acc[nt], 0, 0, 0);
            const int m0 = 16 * mt + 4 * lg;
            const float4 b1v = *(const float4*)(b1 + m0);
            const unsigned m2 = (unsigned)(2 * m0);
            #pragma unroll
            for (int nt = 0; nt < 4; ++nt) {
                const int d = 16 * nt + lr;
                const float v0 = fmaxf(acc[nt][0] + b1v.x, 0.f);
                const float v1 = fmaxf(acc[nt][1] + b1v.y, 0.f);
                const float v2 = fmaxf(acc[nt][2] + b1v.z, 0.f);
                const float v3 = fmaxf(acc[nt][3] + b1v.w, 0.f);
                *(unsigned long long*)(sl + (unsigned)d * 128 + (m2 ^ swl)) =
                    pack4(v0, v1, v2, v3);
            }
        }
    }
    WAITLDS();                                    // T2b visible

    // ---- step3: T3 = T2b @ W2 -> T3t OVER temp ----
    {
        bf16x8 ta[8], bw2[8];
        #pragma unroll
        for (int mt = 0; mt < 4; ++mt)
            #pragma unroll
            for (int ks = 0; ks < 2; ++ks)
                ta[mt * 2 + ks] = *(const bf16x8*)(sl + (unsigned)(16 * mt + lr) * 128 +
                                                   (((unsigned)(64 * ks + 16 * lg)) ^ swl));
        #pragma unroll
        for (int nt = 0; nt < 4; ++nt)
            #pragma unroll
            for (int ks = 0; ks < 2; ++ks)
                bw2[nt * 2 + ks] = *(const bf16x8*)(W2t + (16 * nt + lr) * HDIM + 32 * ks + 8 * lg);
        WAITLDS();                                // T2b reads done before overwrite
        #pragma unroll
        for (int mt = 0; mt < 4; ++mt) {
            f32x4 acc[4];
            #pragma unroll
            for (int nt = 0; nt < 4; ++nt) acc[nt] = (f32x4){0.f, 0.f, 0.f, 0.f};
            #pragma unroll
            for (int ks = 0; ks < 2; ++ks)
                #pragma unroll
                for (int nt = 0; nt < 4; ++nt)
                    acc[nt] = __builtin_amdgcn_mfma_f32_16x16x32_bf16(ta[mt * 2 + ks], bw2[nt * 2 + ks], acc[nt], 0, 0, 0);
            const unsigned m2 = (unsigned)(2 * (16 * mt + 4 * lg));
            #pragma unroll
            for (int nt = 0; nt < 4; ++nt) {
                const int n = 16 * nt + lr;
                *(unsigned long long*)(sl + (unsigned)n * 128 + (m2 ^ swl)) =
                    pack4(acc[nt][0], acc[nt][1], acc[nt][2], acc[nt][3]);
            }
        }
    }
    WAITLDS();                                    // T3t visible

    // ---- step4: h2 = Ab @ T3 (+b2, relu), pool over nodes ----
    {
        bf16x8 bt3[8];
        #pragma unroll
        for (int nt = 0; nt < 4; ++nt)
            #pragma unroll
            for (int ks = 0; ks < 2; ++ks)
                bt3[nt * 2 + ks] = *(const bf16x8*)(sl + (unsigned)(16 * nt + lr) * 128 +
                                                    (((unsigned)(64 * ks + 16 * lg)) ^ swl));
        float b2v[4], p[4];
        #pragma unroll
        for (int nt = 0; nt < 4; ++nt) { b2v[nt] = b2[16 * nt + lr]; p[nt] = 0.f; }
        #pragma unroll
        for (int mt = 0; mt < 4; ++mt) {
            f32x4 acc[4];
            #pragma unroll
            for (int nt = 0; nt < 4; ++nt) acc[nt] = (f32x4){0.f, 0.f, 0.f, 0.f};
            #pragma unroll
            for (int ks = 0; ks < 2; ++ks)
                #pragma unroll
                for (int nt = 0; nt < 4; ++nt)
                    acc[nt] = __builtin_amdgcn_mfma_f32_16x16x32_bf16(ahat[mt * 2 + ks], bt3[nt * 2 + ks], acc[nt], 0, 0, 0);
            #pragma unroll
            for (int nt = 0; nt < 4; ++nt) {
                #pragma unroll
                for (int j = 0; j < 4; ++j) p[nt] += fmaxf(acc[nt][j] + b2v[nt], 0.f);
            }
        }
        #pragma unroll
        for (int nt = 0; nt < 4; ++nt) {
            p[nt] += __shfl_xor(p[nt], 16, 64);
            p[nt] += __shfl_xor(p[nt], 32, 64);
        }
        if (lg == 0) {
            float* hout = hbuf + ((size_t)drug * B_PAIRS + b) * HDIM;
            #pragma unroll
            for (int nt = 0; nt < 4; ++nt) hout[16 * nt + lr] = p[nt] * (1.0f / 64.0f);
        }
    }
}

// ---------------------------------------------------------------------------
// Kernel 2: fused MLP (R5-proven version, unchanged).
// ---------------------------------------------------------------------------
__global__ __launch_bounds__(256)
void fused_mlp_kernel(const float* __restrict__ fp1, const float* __restrict__ fp2,
                      const float* __restrict__ hbuf,
                      const unsigned short* __restrict__ Wm1t,  // [256][4224] bf16
                      const float* __restrict__ bm1, const float* __restrict__ Wm2,
                      const float* __restrict__ bm2, float* __restrict__ out) {
    __shared__ __align__(16) unsigned char lds[8448];
    float* pool = (float*)(lds + 8192);            // 64 floats
    const int t = threadIdx.x;
    const int lane = t & 63, wid = t >> 6;
    const int lr = lane & 15, lg = lane >> 4;
    const int pair0 = blockIdx.x * 16;

    const int r  = t >> 4;                         // staging pair row 0..15
    const int kc = (t & 15) << 3;                  // staging k-offset (floats)
    const int pr = pair0 + r;
    const unsigned wOff = (unsigned)r * 256 + (((unsigned)(2 * kc)) ^ ((unsigned)(r & 7) << 4));

    f32x4 acc[4];
    #pragma unroll
    for (int nf = 0; nf < 4; ++nf) acc[nf] = (f32x4){0.f, 0.f, 0.f, 0.f};

    const unsigned short* brow[4];
    #pragma unroll
    for (int nf = 0; nf < 4; ++nf)
        brow[nf] = Wm1t + (size_t)(64 * wid + 16 * nf + lr) * KTOT + 8 * lg;

    float4 va, vb;
    #define LOAD_A(s)                                                                  \
        {                                                                              \
            const float* src;                                                          \
            if ((s) == 0)                                                              \
                src = (kc < 64) ? hbuf + (size_t)pr * HDIM + kc                        \
                                : hbuf + (size_t)(B_PAIRS + pr) * HDIM + (kc - 64);    \
            else if ((s) <= 16)                                                        \
                src = fp1 + (size_t)pr * FPDIM + ((s) - 1) * 128 + kc;                 \
            else                                                                       \
                src = fp2 + (size_t)pr * FPDIM + ((s) - 17) * 128 + kc;                \
            va = ((const float4*)src)[0];                                              \
            vb = ((const float4*)src)[1];                                              \
        }
    #define STORE_A(base)                                                              \
        *(uint4*)((base) + wOff) = make_uint4(pack2(va.x, va.y), pack2(va.z, va.w),    \
                                              pack2(vb.x, vb.y), pack2(vb.z, vb.w));

    LOAD_A(0);
    STORE_A(lds);
    for (int s = 0; s < 33; ++s) {
        const bool more = (s + 1 < 33);
        if (more) LOAD_A(s + 1);                   // issue next-step globals early
        __syncthreads();                           // buf[s&1] ready; prev reads drained
        const unsigned char* buf = lds + (unsigned)((s & 1) << 12);
        const unsigned asw = (unsigned)(lr & 7) << 4;
        const int kglob = s << 7;
        #pragma unroll
        for (int ks = 0; ks < 4; ++ks) {
            const unsigned kb = (unsigned)(64 * ks + 16 * lg);
            const bf16x8 a = *(const bf16x8*)(buf + (unsigned)lr * 256 + (kb ^ asw));
            #pragma unroll
            for (int nf = 0; nf < 4; ++nf) {
                const bf16x8 bw = *(const bf16x8*)(brow[nf] + kglob + 32 * ks);
                acc[nf] = __builtin_amdgcn_mfma_f32_16x16x32_bf16(a, bw, acc[nf], 0, 0, 0);
            }
        }
        if (more) STORE_A(lds + (unsigned)(((s + 1) & 1) << 12));
    }

    // epilogue: bias, relu, dot Wm2, reduce over n, sigmoid
    float bm1v[4], wm2v[4];
    #pragma unroll
    for (int nf = 0; nf < 4; ++nf) {
        const int n = 64 * wid + 16 * nf + lr;
        bm1v[nf] = bm1[n];
        wm2v[nf] = Wm2[n];
    }
    #pragma unroll
    for (int reg = 0; reg < 4; ++reg) {            // row m = 4*lg + reg
        float p = 0.f;
        #pragma unroll
        for (int nf = 0; nf < 4; ++nf)
            p += fmaxf(acc[nf][reg] + bm1v[nf], 0.f) * wm2v[nf];
        p += __shfl_xor(p, 1, 64);
        p += __shfl_xor(p, 2, 64);
        p += __shfl_xor(p, 4, 64);
        p += __shfl_xor(p, 8, 64);
        if (lr == 0) pool[wid * 16 + 4 * lg + reg] = p;
    }
    __syncthreads();
    if (t < 16) {
        const float y = pool[t] + pool[16 + t] + pool[32 + t] + pool[48 + t] + bm2[0];
        out[pair0 + t] = 1.0f / (1.0f + expf(-y));
    }
    #undef LOAD_A
    #undef STORE_A
}

extern "C" void kernel_launch(void* const* d_in, const int* in_sizes, int n_in,
                              void* d_out, int out_size, void* d_ws, size_t ws_size,
                              hipStream_t stream) {
    const float* x1  = (const float*)d_in[0];
    const float* x2  = (const float*)d_in[1];
    const int*   e1  = (const int*)d_in[2];
    const int*   e2  = (const int*)d_in[3];
    const float* fp1 = (const float*)d_in[4];
    const float* fp2 = (const float*)d_in[5];
    const float* W1  = (const float*)d_in[6];
    const float* b1  = (const float*)d_in[7];
    const float* W2  = (const float*)d_in[8];
    const float* b2  = (const float*)d_in[9];
    const float* Wm1 = (const float*)d_in[10];
    const float* bm1 = (const float*)d_in[11];
    const float* Wm2 = (const float*)d_in[12];
    const float* bm2 = (const float*)d_in[13];
    float* out  = (float*)d_out;

    float* hbuf = (float*)d_ws;                                          // 2 MB
    unsigned short* W1t  = (unsigned short*)((char*)d_ws + (2 << 20));   // 16 KB
    unsigned short* W2t  = W1t + HDIM * FDIM;                            // 8 KB
    unsigned short* Wm1t = (unsigned short*)((char*)d_ws + (3 << 20));   // 2.16 MB

    hipLaunchKernelGGL(prep_weights, dim3(16), dim3(256), 0, stream, W1, W2, W1t, W2t);
    hipLaunchKernelGGL(prep_wm1, dim3(132, 8), dim3(256), 0, stream, Wm1, Wm1t);
    hipLaunchKernelGGL(encode_kernel, dim3(2 * B_PAIRS / 4), dim3(256), 0, stream,
                       x1, x2, e1, e2, W1t, b1, W2t, b2, hbuf);
    hipLaunchKernelGGL(fused_mlp_kernel, dim3(B_PAIRS / 16), dim3(256), 0, stream,
                       fp1, fp2, hbuf, Wm1t, bm1, Wm2, bm2, out);
}

// Round 17
// 172.089 us; speedup vs baseline: 1.1823x; 1.1823x over previous
//
#include <hip/hip_runtime.h>
#include <math.h>

#define B_PAIRS 4096
#define NNODES  64
#define NEDGES  256
#define FDIM    128
#define HDIM    64
#define FPDIM   2048
#define MDIM    256
#define KTOT    4224   // 2*HDIM + 2*FPDIM

typedef __attribute__((ext_vector_type(4))) float f32x4;
typedef __bf16 bf16x8 __attribute__((ext_vector_type(8)));

__device__ __forceinline__ unsigned short f2bf(float f) {
    return __builtin_bit_cast(unsigned short, (__bf16)f);
}
__device__ __forceinline__ unsigned pack2(float a, float b) {
    return (unsigned)f2bf(a) | ((unsigned)f2bf(b) << 16);
}
__device__ __forceinline__ unsigned long long pack4(float a, float b, float c, float d) {
    return (unsigned long long)pack2(a, b) | ((unsigned long long)pack2(c, d) << 32);
}

// ---------------------------------------------------------------------------
// Kernel 0a: W1t[n][k]=W1[k][n], W2t[n][k]=W2[k][n] (bf16), grid-strided.
// ---------------------------------------------------------------------------
__global__ void prep_weights(const float* __restrict__ W1, const float* __restrict__ W2,
                             unsigned short* __restrict__ W1t, unsigned short* __restrict__ W2t) {
    const int t0 = blockIdx.x * 256 + threadIdx.x;
    const int stride = gridDim.x * 256;
    for (int i = t0; i < HDIM * FDIM; i += stride) {
        const int n = i >> 7, k = i & 127;
        W1t[i] = f2bf(W1[k * HDIM + n]);
    }
    for (int i = t0; i < HDIM * HDIM; i += stride) {
        const int n = i >> 6, k = i & 63;
        W2t[i] = f2bf(W2[k * HDIM + n]);
    }
}

// ---------------------------------------------------------------------------
// Kernel 0b: Wm1t[n][k] = bf16(Wm1[k][n]), n<256, k<4224. Tiled 32x32 via LDS.
// ---------------------------------------------------------------------------
__global__ __launch_bounds__(256)
void prep_wm1(const float* __restrict__ Wm1, unsigned short* __restrict__ Wm1t) {
    __shared__ float tile[32][33];
    const int k0 = blockIdx.x * 32, n0 = blockIdx.y * 32;
    const int t = threadIdx.x;
    const int c = t & 31, r8 = t >> 5;
    #pragma unroll
    for (int rr = r8; rr < 32; rr += 8)
        tile[rr][c] = Wm1[(size_t)(k0 + rr) * MDIM + n0 + c];
    __syncthreads();
    #pragma unroll
    for (int j = 0; j < 4; ++j) {
        const int n = n0 + r8 + 8 * j;
        Wm1t[(size_t)n * KTOT + k0 + c] = f2bf(tile[c][r8 + 8 * j]);
    }
}

#define WAITLDS() do { __asm__ volatile("s_waitcnt lgkmcnt(0)" ::: "memory"); \
                       __builtin_amdgcn_sched_barrier(0); } while (0)

// ---------------------------------------------------------------------------
// Kernel 1: per-graph GCN encoder — R10-VERIFIED body (one graph per wave,
// 64-thread blocks, zero barriers; A-hat entirely in registers; single 8K
// temp with cnt overlaid). Encode ~110 us, spill-free (VGPR ~104).
//   [   0, 8448)  cnt u32[64][33] (early); temp bf16 8K [0,8192) after
//   [8448, 8704)  nrm[64]
//   [8704, 8960)  deg[64]
// ---------------------------------------------------------------------------
__global__ __launch_bounds__(64, 2)
void encode_kernel(const float* __restrict__ x1, const float* __restrict__ x2,
                   const int* __restrict__ e1, const int* __restrict__ e2,
                   const unsigned short* __restrict__ W1t, const float* __restrict__ b1,
                   const unsigned short* __restrict__ W2t, const float* __restrict__ b2,
                   float* __restrict__ hbuf) {
    __shared__ __align__(16) unsigned char lds[8960];
    const int gid  = blockIdx.x;                  // 0..8191 = one graph
    const int drug = gid >> 12;
    const int b    = gid & (B_PAIRS - 1);
    const float* x  = (drug ? x2 : x1) + (size_t)b * NNODES * FDIM;
    const int*   eg = (drug ? e2 : e1) + (size_t)b * 2 * NEDGES;

    const int t  = threadIdx.x;                   // lane 0..63
    const int lr = t & 15, lg = t >> 4;
    const unsigned swl = (unsigned)(lr & 7) << 4; // row swizzle (rows ≡ lr mod 8)

    unsigned* cnt = (unsigned*)lds;               // u32[64][33]
    float*    nrm = (float*)(lds + 8448);
    int*      deg = (int*)(lds + 8704);

    // ---- fire first half of x loads (mt 0,1) ----
    float4 xalo[16];
    #pragma unroll
    for (int mt = 0; mt < 2; ++mt) {
        const float* xr = x + (size_t)(16 * mt + lr) * FDIM + 8 * lg;
        #pragma unroll
        for (int ks = 0; ks < 4; ++ks) {
            xalo[mt * 8 + 2 * ks]     = ((const float4*)(xr + 32 * ks))[0];
            xalo[mt * 8 + 2 * ks + 1] = ((const float4*)(xr + 32 * ks))[1];
        }
    }
    // edges straight to registers (4 edges/lane)
    const int4 s4 = ((const int4*)eg)[t];
    const int4 d4 = ((const int4*)eg)[t + 64];

    // ---- zero cnt (2112 u32) + deg ----
    #pragma unroll
    for (int i = 0; i < 8; ++i) ((uint4*)cnt)[t + 64 * i] = make_uint4(0, 0, 0, 0);
    if (t < 16) ((uint4*)cnt)[512 + t] = make_uint4(0, 0, 0, 0);
    deg[t] = 0;
    WAITLDS();

    // ---- degree + multiplicity atomics (this wave only) ----
    {
        const int ss[4] = {s4.x, s4.y, s4.z, s4.w};
        const int dd[4] = {d4.x, d4.y, d4.z, d4.w};
        #pragma unroll
        for (int i = 0; i < 4; ++i) {
            atomicAdd(&deg[dd[i]], 1);
            atomicAdd(&cnt[dd[i] * 33 + (ss[i] >> 1)], 1u << ((ss[i] & 1) * 16));
        }
    }
    WAITLDS();

    // ---- fire second half of x loads (mt 2,3) ----
    float4 xahi[16];
    #pragma unroll
    for (int mt = 0; mt < 2; ++mt) {
        const float* xr2 = x + (size_t)(16 * (mt + 2) + lr) * FDIM + 8 * lg;
        #pragma unroll
        for (int ks = 0; ks < 4; ++ks) {
            xahi[mt * 8 + 2 * ks]     = ((const float4*)(xr2 + 32 * ks))[0];
            xahi[mt * 8 + 2 * ks + 1] = ((const float4*)(xr2 + 32 * ks))[1];
        }
    }

    nrm[t] = rsqrtf((float)deg[t] + 1.0f);
    WAITLDS();

    // hoist step-1 W1t B-fragments (L2-hot)
    bf16x8 bw1[16];
    #pragma unroll
    for (int nt = 0; nt < 4; ++nt)
        #pragma unroll
        for (int ks = 0; ks < 4; ++ks)
            bw1[nt * 4 + ks] = *(const bf16x8*)(W1t + (16 * nt + lr) * FDIM + 32 * ks + 8 * lg);

    // ---- build A-hat FRAGMENTS in registers ----
    // frag(q,ks): rows 16q+lr, cols 32ks+8lg+e. Serves BOTH step2's B-operand
    // and step4's A-operand (identical lane mapping).
    bf16x8 ahat[8];
    {
        const float ncol[2][8] = {
            { nrm[8 * lg + 0], nrm[8 * lg + 1], nrm[8 * lg + 2], nrm[8 * lg + 3],
              nrm[8 * lg + 4], nrm[8 * lg + 5], nrm[8 * lg + 6], nrm[8 * lg + 7] },
            { nrm[32 + 8 * lg + 0], nrm[32 + 8 * lg + 1], nrm[32 + 8 * lg + 2], nrm[32 + 8 * lg + 3],
              nrm[32 + 8 * lg + 4], nrm[32 + 8 * lg + 5], nrm[32 + 8 * lg + 6], nrm[32 + 8 * lg + 7] }
        };
        #pragma unroll
        for (int q = 0; q < 4; ++q) {
            const int r = 16 * q + lr;
            const float nr = nrm[r];
            #pragma unroll
            for (int ks = 0; ks < 2; ++ks) {
                const int c0 = 32 * ks + 8 * lg;          // even, /2 -> word idx
                const uint4 w = *(const uint4*)(cnt + r * 33 + (c0 >> 1));
                const unsigned ww[4] = { w.x, w.y, w.z, w.w };
                bf16x8 f;
                #pragma unroll
                for (int e = 0; e < 8; ++e) {
                    const int c = c0 + e;
                    const unsigned m = (e & 1) ? (ww[e >> 1] >> 16) : (ww[e >> 1] & 0xffffu);
                    const float v = (float)(m + (r == c ? 1u : 0u)) * nr * ncol[ks][e];
                    f[e] = (__bf16)v;
                }
                ahat[q * 2 + ks] = f;
            }
        }
    }
    WAITLDS();                                    // all cnt reads retired; temp free

    // ---- step1: T1 = X @ W1 -> T1t[featH][node] at temp (0) ----
    #pragma unroll
    for (int half = 0; half < 2; ++half) {
        const float4* xs = half ? xahi : xalo;
        #pragma unroll
        for (int m2i = 0; m2i < 2; ++m2i) {
            const int mt = half * 2 + m2i;
            f32x4 acc[4];
            #pragma unroll
            for (int nt = 0; nt < 4; ++nt) acc[nt] = (f32x4){0.f, 0.f, 0.f, 0.f};
            #pragma unroll
            for (int ks = 0; ks < 4; ++ks) {
                bf16x8 a;
                const float4 u = xs[m2i * 8 + 2 * ks], v = xs[m2i * 8 + 2 * ks + 1];
                a[0] = (__bf16)u.x; a[1] = (__bf16)u.y; a[2] = (__bf16)u.z; a[3] = (__bf16)u.w;
                a[4] = (__bf16)v.x; a[5] = (__bf16)v.y; a[6] = (__bf16)v.z; a[7] = (__bf16)v.w;
                #pragma unroll
                for (int nt = 0; nt < 4; ++nt)
                    acc[nt] = __builtin_amdgcn_mfma_f32_16x16x32_bf16(a, bw1[nt * 4 + ks], acc[nt], 0, 0, 0);
            }
            const unsigned m2 = (unsigned)(2 * (16 * mt + 4 * lg));
            #pragma unroll
            for (int nt = 0; nt < 4; ++nt) {
                const int f = 16 * nt + lr;
                *(unsigned long long*)(lds + (unsigned)f * 128 + (m2 ^ swl)) =
                    pack4(acc[nt][0], acc[nt][1], acc[nt][2], acc[nt][3]);
            }
        }
    }
    WAITLDS();                                    // T1t visible

    // ---- step2: T2^T = T1t @ A^T (+b1, relu) -> T2b OVER temp ----
    {
        bf16x8 ta[8];
        #pragma unroll
        for (int mt = 0; mt < 4; ++mt)
            #pragma unroll
            for (int ks = 0; ks < 2; ++ks)
                ta[mt * 2 + ks] = *(const bf16x8*)(lds + (unsigned)(16 * mt + lr) * 128 +
                                                   (((unsigned)(64 * ks + 16 * lg)) ^ swl));
        WAITLDS();                                // reads done before overwrite
        #pragma unroll
        for (int mt = 0; mt < 4; ++mt) {
            f32x4 acc[4];
            #pragma unroll
            for (int nt = 0; nt < 4; ++nt) acc[nt] = (f32x4){0.f, 0.f, 0.f, 0.f};
            #pragma unroll
            for (int ks = 0; ks < 2; ++ks)
                #pragma unroll
                for (int nt = 0; nt < 4; ++nt)
                    acc[nt] = __builtin_amdgcn_mfma_f32_16x16x32_bf16(ta[mt * 2 + ks], ahat[nt * 2 + ks], acc[nt], 0, 0, 0);
            const int m0 = 16 * mt + 4 * lg;
            const float4 b1v = *(const float4*)(b1 + m0);
            const unsigned m2 = (unsigned)(2 * m0);
            #pragma unroll
            for (int nt = 0; nt < 4; ++nt) {
                const int d = 16 * nt + lr;
                const float v0 = fmaxf(acc[nt][0] + b1v.x, 0.f);
                const float v1 = fmaxf(acc[nt][1] + b1v.y, 0.f);
                const float v2 = fmaxf(acc[nt][2] + b1v.z, 0.f);
                const float v3 = fmaxf(acc[nt][3] + b1v.w, 0.f);
                *(unsigned long long*)(lds + (unsigned)d * 128 + (m2 ^ swl)) =
                    pack4(v0, v1, v2, v3);
            }
        }
    }
    WAITLDS();                                    // T2b visible

    // ---- step3: T3 = T2b @ W2 -> T3t OVER temp ----
    {
        bf16x8 ta[8], bw2[8];
        #pragma unroll
        for (int mt = 0; mt < 4; ++mt)
            #pragma unroll
            for (int ks = 0; ks < 2; ++ks)
                ta[mt * 2 + ks] = *(const bf16x8*)(lds + (unsigned)(16 * mt + lr) * 128 +
                                                   (((unsigned)(64 * ks + 16 * lg)) ^ swl));
        #pragma unroll
        for (int nt = 0; nt < 4; ++nt)
            #pragma unroll
            for (int ks = 0; ks < 2; ++ks)
                bw2[nt * 2 + ks] = *(const bf16x8*)(W2t + (16 * nt + lr) * HDIM + 32 * ks + 8 * lg);
        WAITLDS();                                // T2b reads done before overwrite
        #pragma unroll
        for (int mt = 0; mt < 4; ++mt) {
            f32x4 acc[4];
            #pragma unroll
            for (int nt = 0; nt < 4; ++nt) acc[nt] = (f32x4){0.f, 0.f, 0.f, 0.f};
            #pragma unroll
            for (int ks = 0; ks < 2; ++ks)
                #pragma unroll
                for (int nt = 0; nt < 4; ++nt)
                    acc[nt] = __builtin_amdgcn_mfma_f32_16x16x32_bf16(ta[mt * 2 + ks], bw2[nt * 2 + ks], acc[nt], 0, 0, 0);
            const unsigned m2 = (unsigned)(2 * (16 * mt + 4 * lg));
            #pragma unroll
            for (int nt = 0; nt < 4; ++nt) {
                const int n = 16 * nt + lr;
                *(unsigned long long*)(lds + (unsigned)n * 128 + (m2 ^ swl)) =
                    pack4(acc[nt][0], acc[nt][1], acc[nt][2], acc[nt][3]);
            }
        }
    }
    WAITLDS();                                    // T3t visible

    // ---- step4: h2 = Ab @ T3 (+b2, relu), pool over nodes ----
    {
        bf16x8 bt3[8];
        #pragma unroll
        for (int nt = 0; nt < 4; ++nt)
            #pragma unroll
            for (int ks = 0; ks < 2; ++ks)
                bt3[nt * 2 + ks] = *(const bf16x8*)(lds + (unsigned)(16 * nt + lr) * 128 +
                                                    (((unsigned)(64 * ks + 16 * lg)) ^ swl));
        float b2v[4], p[4];
        #pragma unroll
        for (int nt = 0; nt < 4; ++nt) { b2v[nt] = b2[16 * nt + lr]; p[nt] = 0.f; }
        #pragma unroll
        for (int mt = 0; mt < 4; ++mt) {
            f32x4 acc[4];
            #pragma unroll
            for (int nt = 0; nt < 4; ++nt) acc[nt] = (f32x4){0.f, 0.f, 0.f, 0.f};
            #pragma unroll
            for (int ks = 0; ks < 2; ++ks)
                #pragma unroll
                for (int nt = 0; nt < 4; ++nt)
                    acc[nt] = __builtin_amdgcn_mfma_f32_16x16x32_bf16(ahat[mt * 2 + ks], bt3[nt * 2 + ks], acc[nt], 0, 0, 0);
            #pragma unroll
            for (int nt = 0; nt < 4; ++nt) {
                #pragma unroll
                for (int j = 0; j < 4; ++j) p[nt] += fmaxf(acc[nt][j] + b2v[nt], 0.f);
            }
        }
        #pragma unroll
        for (int nt = 0; nt < 4; ++nt) {
            p[nt] += __shfl_xor(p[nt], 16, 64);
            p[nt] += __shfl_xor(p[nt], 32, 64);
        }
        if (lg == 0) {
            float* hout = hbuf + ((size_t)drug * B_PAIRS + b) * HDIM;
            #pragma unroll
            for (int nt = 0; nt < 4; ++nt) hout[16 * nt + lr] = p[nt] * (1.0f / 64.0f);
        }
    }
}

// ---------------------------------------------------------------------------
// Kernel 2: fused MLP, N-SPLIT x2. Grid (256, 2): blockIdx.y = ns picks cols
// [128*ns, 128*ns+128). Each block: full K (33 steps) for 16 pairs x 128
// cols -> relu(hidden)*Wm2 partial dot -> P[ns][pair]. 512 blocks = 2/CU =
// 8 waves/CU (2x latency hiding vs R5's 1 block/CU); 8 MFMAs/step chain.
// ---------------------------------------------------------------------------
__global__ __launch_bounds__(256)
void mlp_half_kernel(const float* __restrict__ fp1, const float* __restrict__ fp2,
                     const float* __restrict__ hbuf,
                     const unsigned short* __restrict__ Wm1t,  // [256][4224] bf16
                     const float* __restrict__ bm1, const float* __restrict__ Wm2,
                     float* __restrict__ P) {
    __shared__ __align__(16) unsigned char lds[8448];
    float* pool = (float*)(lds + 8192);            // 64 floats
    const int t = threadIdx.x;
    const int lane = t & 63, wid = t >> 6;
    const int lr = lane & 15, lg = lane >> 4;
    const int pair0 = blockIdx.x * 16;
    const int ns = blockIdx.y;                     // N-half: cols 128*ns..+128

    const int r  = t >> 4;                         // staging pair row 0..15
    const int kc = (t & 15) << 3;                  // staging k-offset (floats)
    const int pr = pair0 + r;
    const unsigned wOff = (unsigned)r * 256 + (((unsigned)(2 * kc)) ^ ((unsigned)(r & 7) << 4));

    f32x4 acc[2];
    acc[0] = (f32x4){0.f, 0.f, 0.f, 0.f};
    acc[1] = (f32x4){0.f, 0.f, 0.f, 0.f};

    const unsigned short* brow[2];
    #pragma unroll
    for (int nf = 0; nf < 2; ++nf)
        brow[nf] = Wm1t + (size_t)(128 * ns + 32 * wid + 16 * nf + lr) * KTOT + 8 * lg;

    float4 va, vb;
    #define LOAD_A(s)                                                                  \
        {                                                                              \
            const float* src;                                                          \
            if ((s) == 0)                                                              \
                src = (kc < 64) ? hbuf + (size_t)pr * HDIM + kc                        \
                                : hbuf + (size_t)(B_PAIRS + pr) * HDIM + (kc - 64);    \
            else if ((s) <= 16)                                                        \
                src = fp1 + (size_t)pr * FPDIM + ((s) - 1) * 128 + kc;                 \
            else                                                                       \
                src = fp2 + (size_t)pr * FPDIM + ((s) - 17) * 128 + kc;                \
            va = ((const float4*)src)[0];                                              \
            vb = ((const float4*)src)[1];                                              \
        }
    #define STORE_A(base)                                                              \
        *(uint4*)((base) + wOff) = make_uint4(pack2(va.x, va.y), pack2(va.z, va.w),    \
                                              pack2(vb.x, vb.y), pack2(vb.z, vb.w));

    LOAD_A(0);
    STORE_A(lds);
    for (int s = 0; s < 33; ++s) {
        const bool more = (s + 1 < 33);
        if (more) LOAD_A(s + 1);                   // issue next-step globals early
        __syncthreads();                           // buf[s&1] ready; prev reads drained
        const unsigned char* buf = lds + (unsigned)((s & 1) << 12);
        const unsigned asw = (unsigned)(lr & 7) << 4;
        const int kglob = s << 7;
        #pragma unroll
        for (int ks = 0; ks < 4; ++ks) {
            const unsigned kb = (unsigned)(64 * ks + 16 * lg);
            const bf16x8 a = *(const bf16x8*)(buf + (unsigned)lr * 256 + (kb ^ asw));
            #pragma unroll
            for (int nf = 0; nf < 2; ++nf) {
                const bf16x8 bw = *(const bf16x8*)(brow[nf] + kglob + 32 * ks);
                acc[nf] = __builtin_amdgcn_mfma_f32_16x16x32_bf16(a, bw, acc[nf], 0, 0, 0);
            }
        }
        if (more) STORE_A(lds + (unsigned)(((s + 1) & 1) << 12));
    }

    // epilogue: bias, relu, dot Wm2 over this block's 128 cols, reduce
    float bm1v[2], wm2v[2];
    #pragma unroll
    for (int nf = 0; nf < 2; ++nf) {
        const int n = 128 * ns + 32 * wid + 16 * nf + lr;
        bm1v[nf] = bm1[n];
        wm2v[nf] = Wm2[n];
    }
    #pragma unroll
    for (int reg = 0; reg < 4; ++reg) {            // row m = 4*lg + reg
        float p = 0.f;
        #pragma unroll
        for (int nf = 0; nf < 2; ++nf)
            p += fmaxf(acc[nf][reg] + bm1v[nf], 0.f) * wm2v[nf];
        p += __shfl_xor(p, 1, 64);
        p += __shfl_xor(p, 2, 64);
        p += __shfl_xor(p, 4, 64);
        p += __shfl_xor(p, 8, 64);
        if (lr == 0) pool[wid * 16 + 4 * lg + reg] = p;
    }
    __syncthreads();
    if (t < 16)
        P[(size_t)ns * B_PAIRS + pair0 + t] = pool[t] + pool[16 + t] + pool[32 + t] + pool[48 + t];
    #undef LOAD_A
    #undef STORE_A
}

// ---------------------------------------------------------------------------
// Kernel 3: combine the two N-half partial dots, add bm2, sigmoid.
// ---------------------------------------------------------------------------
__global__ __launch_bounds__(256)
void combine_kernel(const float* __restrict__ P, const float* __restrict__ bm2,
                    float* __restrict__ out) {
    const int i = blockIdx.x * 256 + threadIdx.x;
    const float y = P[i] + P[B_PAIRS + i] + bm2[0];
    out[i] = 1.0f / (1.0f + expf(-y));
}

extern "C" void kernel_launch(void* const* d_in, const int* in_sizes, int n_in,
                              void* d_out, int out_size, void* d_ws, size_t ws_size,
                              hipStream_t stream) {
    const float* x1  = (const float*)d_in[0];
    const float* x2  = (const float*)d_in[1];
    const int*   e1  = (const int*)d_in[2];
    const int*   e2  = (const int*)d_in[3];
    const float* fp1 = (const float*)d_in[4];
    const float* fp2 = (const float*)d_in[5];
    const float* W1  = (const float*)d_in[6];
    const float* b1  = (const float*)d_in[7];
    const float* W2  = (const float*)d_in[8];
    const float* b2  = (const float*)d_in[9];
    const float* Wm1 = (const float*)d_in[10];
    const float* bm1 = (const float*)d_in[11];
    const float* Wm2 = (const float*)d_in[12];
    const float* bm2 = (const float*)d_in[13];
    float* out  = (float*)d_out;

    float* hbuf = (float*)d_ws;                                          // 2 MB
    unsigned short* W1t  = (unsigned short*)((char*)d_ws + (2 << 20));   // 16 KB
    unsigned short* W2t  = W1t + HDIM * FDIM;                            // 8 KB
    unsigned short* Wm1t = (unsigned short*)((char*)d_ws + (3 << 20));   // 2.16 MB
    float* P = (float*)((char*)d_ws + (6 << 20));                        // 32 KB

    hipLaunchKernelGGL(prep_weights, dim3(16), dim3(256), 0, stream, W1, W2, W1t, W2t);
    hipLaunchKernelGGL(prep_wm1, dim3(132, 8), dim3(256), 0, stream, Wm1, Wm1t);
    hipLaunchKernelGGL(encode_kernel, dim3(2 * B_PAIRS), dim3(64), 0, stream,
                       x1, x2, e1, e2, W1t, b1, W2t, b2, hbuf);
    hipLaunchKernelGGL(mlp_half_kernel, dim3(B_PAIRS / 16, 2), dim3(256), 0, stream,
                       fp1, fp2, hbuf, Wm1t, bm1, Wm2, P);
    hipLaunchKernelGGL(combine_kernel, dim3(B_PAIRS / 256), dim3(256), 0, stream,
                       P, bm2, out);
}

// Round 18
// 160.682 us; speedup vs baseline: 1.2662x; 1.0710x over previous
//
#include <hip/hip_runtime.h>
#include <math.h>

#define B_PAIRS 4096
#define NNODES  64
#define NEDGES  256
#define FDIM    128
#define HDIM    64
#define FPDIM   2048
#define MDIM    256
#define KTOT    4224   // 2*HDIM + 2*FPDIM

typedef __attribute__((ext_vector_type(4))) float f32x4;
typedef __bf16 bf16x8 __attribute__((ext_vector_type(8)));

__device__ __forceinline__ unsigned short f2bf(float f) {
    return __builtin_bit_cast(unsigned short, (__bf16)f);
}
__device__ __forceinline__ unsigned pack2(float a, float b) {
    return (unsigned)f2bf(a) | ((unsigned)f2bf(b) << 16);
}
__device__ __forceinline__ unsigned long long pack4(float a, float b, float c, float d) {
    return (unsigned long long)pack2(a, b) | ((unsigned long long)pack2(c, d) << 32);
}

// ---------------------------------------------------------------------------
// Kernel 0a: W1t[n][k]=W1[k][n], W2t[n][k]=W2[k][n] (bf16), grid-strided.
// ---------------------------------------------------------------------------
__global__ void prep_weights(const float* __restrict__ W1, const float* __restrict__ W2,
                             unsigned short* __restrict__ W1t, unsigned short* __restrict__ W2t) {
    const int t0 = blockIdx.x * 256 + threadIdx.x;
    const int stride = gridDim.x * 256;
    for (int i = t0; i < HDIM * FDIM; i += stride) {
        const int n = i >> 7, k = i & 127;
        W1t[i] = f2bf(W1[k * HDIM + n]);
    }
    for (int i = t0; i < HDIM * HDIM; i += stride) {
        const int n = i >> 6, k = i & 63;
        W2t[i] = f2bf(W2[k * HDIM + n]);
    }
}

// ---------------------------------------------------------------------------
// Kernel 0b: Wm1t[n][k] = bf16(Wm1[k][n]), n<256, k<4224. Tiled 32x32 via LDS.
// ---------------------------------------------------------------------------
__global__ __launch_bounds__(256)
void prep_wm1(const float* __restrict__ Wm1, unsigned short* __restrict__ Wm1t) {
    __shared__ float tile[32][33];
    const int k0 = blockIdx.x * 32, n0 = blockIdx.y * 32;
    const int t = threadIdx.x;
    const int c = t & 31, r8 = t >> 5;
    #pragma unroll
    for (int rr = r8; rr < 32; rr += 8)
        tile[rr][c] = Wm1[(size_t)(k0 + rr) * MDIM + n0 + c];
    __syncthreads();
    #pragma unroll
    for (int j = 0; j < 4; ++j) {
        const int n = n0 + r8 + 8 * j;
        Wm1t[(size_t)n * KTOT + k0 + c] = f2bf(tile[c][r8 + 8 * j]);
    }
}

#define WAITLDS() do { __asm__ volatile("s_waitcnt lgkmcnt(0)" ::: "memory"); \
                       __builtin_amdgcn_sched_barrier(0); } while (0)

// ---------------------------------------------------------------------------
// Kernel 1: per-graph GCN encoder — R10-VERIFIED BEST (one graph per wave,
// 64-thread blocks, zero barriers; A-hat entirely in registers; single 8K
// LDS temp with cnt overlaid). LDS 8960 B; VGPR ~104, spill-free.
//   [   0, 8448)  cnt u32[64][33] (early); temp bf16 8K [0,8192) after
//   [8448, 8704)  nrm[64]
//   [8704, 8960)  deg[64]
// ---------------------------------------------------------------------------
__global__ __launch_bounds__(64, 2)
void encode_kernel(const float* __restrict__ x1, const float* __restrict__ x2,
                   const int* __restrict__ e1, const int* __restrict__ e2,
                   const unsigned short* __restrict__ W1t, const float* __restrict__ b1,
                   const unsigned short* __restrict__ W2t, const float* __restrict__ b2,
                   float* __restrict__ hbuf) {
    __shared__ __align__(16) unsigned char lds[8960];
    const int gid  = blockIdx.x;                  // 0..8191 = one graph
    const int drug = gid >> 12;
    const int b    = gid & (B_PAIRS - 1);
    const float* x  = (drug ? x2 : x1) + (size_t)b * NNODES * FDIM;
    const int*   eg = (drug ? e2 : e1) + (size_t)b * 2 * NEDGES;

    const int t  = threadIdx.x;                   // lane 0..63
    const int lr = t & 15, lg = t >> 4;
    const unsigned swl = (unsigned)(lr & 7) << 4; // row swizzle (rows ≡ lr mod 8)

    unsigned* cnt = (unsigned*)lds;               // u32[64][33]
    float*    nrm = (float*)(lds + 8448);
    int*      deg = (int*)(lds + 8704);

    // ---- fire first half of x loads (mt 0,1) ----
    float4 xalo[16];
    #pragma unroll
    for (int mt = 0; mt < 2; ++mt) {
        const float* xr = x + (size_t)(16 * mt + lr) * FDIM + 8 * lg;
        #pragma unroll
        for (int ks = 0; ks < 4; ++ks) {
            xalo[mt * 8 + 2 * ks]     = ((const float4*)(xr + 32 * ks))[0];
            xalo[mt * 8 + 2 * ks + 1] = ((const float4*)(xr + 32 * ks))[1];
        }
    }
    // edges straight to registers (4 edges/lane)
    const int4 s4 = ((const int4*)eg)[t];
    const int4 d4 = ((const int4*)eg)[t + 64];

    // ---- zero cnt (2112 u32) + deg ----
    #pragma unroll
    for (int i = 0; i < 8; ++i) ((uint4*)cnt)[t + 64 * i] = make_uint4(0, 0, 0, 0);
    if (t < 16) ((uint4*)cnt)[512 + t] = make_uint4(0, 0, 0, 0);
    deg[t] = 0;
    WAITLDS();

    // ---- degree + multiplicity atomics (this wave only) ----
    {
        const int ss[4] = {s4.x, s4.y, s4.z, s4.w};
        const int dd[4] = {d4.x, d4.y, d4.z, d4.w};
        #pragma unroll
        for (int i = 0; i < 4; ++i) {
            atomicAdd(&deg[dd[i]], 1);
            atomicAdd(&cnt[dd[i] * 33 + (ss[i] >> 1)], 1u << ((ss[i] & 1) * 16));
        }
    }
    WAITLDS();

    // ---- fire second half of x loads (mt 2,3) ----
    float4 xahi[16];
    #pragma unroll
    for (int mt = 0; mt < 2; ++mt) {
        const float* xr2 = x + (size_t)(16 * (mt + 2) + lr) * FDIM + 8 * lg;
        #pragma unroll
        for (int ks = 0; ks < 4; ++ks) {
            xahi[mt * 8 + 2 * ks]     = ((const float4*)(xr2 + 32 * ks))[0];
            xahi[mt * 8 + 2 * ks + 1] = ((const float4*)(xr2 + 32 * ks))[1];
        }
    }

    nrm[t] = rsqrtf((float)deg[t] + 1.0f);
    WAITLDS();

    // hoist step-1 W1t B-fragments (L2-hot)
    bf16x8 bw1[16];
    #pragma unroll
    for (int nt = 0; nt < 4; ++nt)
        #pragma unroll
        for (int ks = 0; ks < 4; ++ks)
            bw1[nt * 4 + ks] = *(const bf16x8*)(W1t + (16 * nt + lr) * FDIM + 32 * ks + 8 * lg);

    // ---- build A-hat FRAGMENTS in registers ----
    // frag(q,ks): rows 16q+lr, cols 32ks+8lg+e. Serves BOTH step2's B-operand
    // and step4's A-operand (identical lane mapping).
    bf16x8 ahat[8];
    {
        const float ncol[2][8] = {
            { nrm[8 * lg + 0], nrm[8 * lg + 1], nrm[8 * lg + 2], nrm[8 * lg + 3],
              nrm[8 * lg + 4], nrm[8 * lg + 5], nrm[8 * lg + 6], nrm[8 * lg + 7] },
            { nrm[32 + 8 * lg + 0], nrm[32 + 8 * lg + 1], nrm[32 + 8 * lg + 2], nrm[32 + 8 * lg + 3],
              nrm[32 + 8 * lg + 4], nrm[32 + 8 * lg + 5], nrm[32 + 8 * lg + 6], nrm[32 + 8 * lg + 7] }
        };
        #pragma unroll
        for (int q = 0; q < 4; ++q) {
            const int r = 16 * q + lr;
            const float nr = nrm[r];
            #pragma unroll
            for (int ks = 0; ks < 2; ++ks) {
                const int c0 = 32 * ks + 8 * lg;          // even, /2 -> word idx
                const uint4 w = *(const uint4*)(cnt + r * 33 + (c0 >> 1));
                const unsigned ww[4] = { w.x, w.y, w.z, w.w };
                bf16x8 f;
                #pragma unroll
                for (int e = 0; e < 8; ++e) {
                    const int c = c0 + e;
                    const unsigned m = (e & 1) ? (ww[e >> 1] >> 16) : (ww[e >> 1] & 0xffffu);
                    const float v = (float)(m + (r == c ? 1u : 0u)) * nr * ncol[ks][e];
                    f[e] = (__bf16)v;
                }
                ahat[q * 2 + ks] = f;
            }
        }
    }
    WAITLDS();                                    // all cnt reads retired; temp free

    // ---- step1: T1 = X @ W1 -> T1t[featH][node] at temp (0) ----
    #pragma unroll
    for (int half = 0; half < 2; ++half) {
        const float4* xs = half ? xahi : xalo;
        #pragma unroll
        for (int m2i = 0; m2i < 2; ++m2i) {
            const int mt = half * 2 + m2i;
            f32x4 acc[4];
            #pragma unroll
            for (int nt = 0; nt < 4; ++nt) acc[nt] = (f32x4){0.f, 0.f, 0.f, 0.f};
            #pragma unroll
            for (int ks = 0; ks < 4; ++ks) {
                bf16x8 a;
                const float4 u = xs[m2i * 8 + 2 * ks], v = xs[m2i * 8 + 2 * ks + 1];
                a[0] = (__bf16)u.x; a[1] = (__bf16)u.y; a[2] = (__bf16)u.z; a[3] = (__bf16)u.w;
                a[4] = (__bf16)v.x; a[5] = (__bf16)v.y; a[6] = (__bf16)v.z; a[7] = (__bf16)v.w;
                #pragma unroll
                for (int nt = 0; nt < 4; ++nt)
                    acc[nt] = __builtin_amdgcn_mfma_f32_16x16x32_bf16(a, bw1[nt * 4 + ks], acc[nt], 0, 0, 0);
            }
            const unsigned m2 = (unsigned)(2 * (16 * mt + 4 * lg));
            #pragma unroll
            for (int nt = 0; nt < 4; ++nt) {
                const int f = 16 * nt + lr;
                *(unsigned long long*)(lds + (unsigned)f * 128 + (m2 ^ swl)) =
                    pack4(acc[nt][0], acc[nt][1], acc[nt][2], acc[nt][3]);
            }
        }
    }
    WAITLDS();                                    // T1t visible

    // ---- step2: T2^T = T1t @ A^T (+b1, relu) -> T2b OVER temp ----
    {
        bf16x8 ta[8];
        #pragma unroll
        for (int mt = 0; mt < 4; ++mt)
            #pragma unroll
            for (int ks = 0; ks < 2; ++ks)
                ta[mt * 2 + ks] = *(const bf16x8*)(lds + (unsigned)(16 * mt + lr) * 128 +
                                                   (((unsigned)(64 * ks + 16 * lg)) ^ swl));
        WAITLDS();                                // reads done before overwrite
        #pragma unroll
        for (int mt = 0; mt < 4; ++mt) {
            f32x4 acc[4];
            #pragma unroll
            for (int nt = 0; nt < 4; ++nt) acc[nt] = (f32x4){0.f, 0.f, 0.f, 0.f};
            #pragma unroll
            for (int ks = 0; ks < 2; ++ks)
                #pragma unroll
                for (int nt = 0; nt < 4; ++nt)
                    acc[nt] = __builtin_amdgcn_mfma_f32_16x16x32_bf16(ta[mt * 2 + ks], ahat[nt * 2 + ks], acc[nt], 0, 0, 0);
            const int m0 = 16 * mt + 4 * lg;
            const float4 b1v = *(const float4*)(b1 + m0);
            const unsigned m2 = (unsigned)(2 * m0);
            #pragma unroll
            for (int nt = 0; nt < 4; ++nt) {
                const int d = 16 * nt + lr;
                const float v0 = fmaxf(acc[nt][0] + b1v.x, 0.f);
                const float v1 = fmaxf(acc[nt][1] + b1v.y, 0.f);
                const float v2 = fmaxf(acc[nt][2] + b1v.z, 0.f);
                const float v3 = fmaxf(acc[nt][3] + b1v.w, 0.f);
                *(unsigned long long*)(lds + (unsigned)d * 128 + (m2 ^ swl)) =
                    pack4(v0, v1, v2, v3);
            }
        }
    }
    WAITLDS();                                    // T2b visible

    // ---- step3: T3 = T2b @ W2 -> T3t OVER temp ----
    {
        bf16x8 ta[8], bw2[8];
        #pragma unroll
        for (int mt = 0; mt < 4; ++mt)
            #pragma unroll
            for (int ks = 0; ks < 2; ++ks)
                ta[mt * 2 + ks] = *(const bf16x8*)(lds + (unsigned)(16 * mt + lr) * 128 +
                                                   (((unsigned)(64 * ks + 16 * lg)) ^ swl));
        #pragma unroll
        for (int nt = 0; nt < 4; ++nt)
            #pragma unroll
            for (int ks = 0; ks < 2; ++ks)
                bw2[nt * 2 + ks] = *(const bf16x8*)(W2t + (16 * nt + lr) * HDIM + 32 * ks + 8 * lg);
        WAITLDS();                                // T2b reads done before overwrite
        #pragma unroll
        for (int mt = 0; mt < 4; ++mt) {
            f32x4 acc[4];
            #pragma unroll
            for (int nt = 0; nt < 4; ++nt) acc[nt] = (f32x4){0.f, 0.f, 0.f, 0.f};
            #pragma unroll
            for (int ks = 0; ks < 2; ++ks)
                #pragma unroll
                for (int nt = 0; nt < 4; ++nt)
                    acc[nt] = __builtin_amdgcn_mfma_f32_16x16x32_bf16(ta[mt * 2 + ks], bw2[nt * 2 + ks], acc[nt], 0, 0, 0);
            const unsigned m2 = (unsigned)(2 * (16 * mt + 4 * lg));
            #pragma unroll
            for (int nt = 0; nt < 4; ++nt) {
                const int n = 16 * nt + lr;
                *(unsigned long long*)(lds + (unsigned)n * 128 + (m2 ^ swl)) =
                    pack4(acc[nt][0], acc[nt][1], acc[nt][2], acc[nt][3]);
            }
        }
    }
    WAITLDS();                                    // T3t visible

    // ---- step4: h2 = Ab @ T3 (+b2, relu), pool over nodes ----
    {
        bf16x8 bt3[8];
        #pragma unroll
        for (int nt = 0; nt < 4; ++nt)
            #pragma unroll
            for (int ks = 0; ks < 2; ++ks)
                bt3[nt * 2 + ks] = *(const bf16x8*)(lds + (unsigned)(16 * nt + lr) * 128 +
                                                    (((unsigned)(64 * ks + 16 * lg)) ^ swl));
        float b2v[4], p[4];
        #pragma unroll
        for (int nt = 0; nt < 4; ++nt) { b2v[nt] = b2[16 * nt + lr]; p[nt] = 0.f; }
        #pragma unroll
        for (int mt = 0; mt < 4; ++mt) {
            f32x4 acc[4];
            #pragma unroll
            for (int nt = 0; nt < 4; ++nt) acc[nt] = (f32x4){0.f, 0.f, 0.f, 0.f};
            #pragma unroll
            for (int ks = 0; ks < 2; ++ks)
                #pragma unroll
                for (int nt = 0; nt < 4; ++nt)
                    acc[nt] = __builtin_amdgcn_mfma_f32_16x16x32_bf16(ahat[mt * 2 + ks], bt3[nt * 2 + ks], acc[nt], 0, 0, 0);
            #pragma unroll
            for (int nt = 0; nt < 4; ++nt) {
                #pragma unroll
                for (int j = 0; j < 4; ++j) p[nt] += fmaxf(acc[nt][j] + b2v[nt], 0.f);
            }
        }
        #pragma unroll
        for (int nt = 0; nt < 4; ++nt) {
            p[nt] += __shfl_xor(p[nt], 16, 64);
            p[nt] += __shfl_xor(p[nt], 32, 64);
        }
        if (lg == 0) {
            float* hout = hbuf + ((size_t)drug * B_PAIRS + b) * HDIM;
            #pragma unroll
            for (int nt = 0; nt < 4; ++nt) hout[16 * nt + lr] = p[nt] * (1.0f / 64.0f);
        }
    }
}

// ---------------------------------------------------------------------------
// Kernel 2: fused MLP (R5-proven version, unchanged).
// ---------------------------------------------------------------------------
__global__ __launch_bounds__(256)
void fused_mlp_kernel(const float* __restrict__ fp1, const float* __restrict__ fp2,
                      const float* __restrict__ hbuf,
                      const unsigned short* __restrict__ Wm1t,  // [256][4224] bf16
                      const float* __restrict__ bm1, const float* __restrict__ Wm2,
                      const float* __restrict__ bm2, float* __restrict__ out) {
    __shared__ __align__(16) unsigned char lds[8448];
    float* pool = (float*)(lds + 8192);            // 64 floats
    const int t = threadIdx.x;
    const int lane = t & 63, wid = t >> 6;
    const int lr = lane & 15, lg = lane >> 4;
    const int pair0 = blockIdx.x * 16;

    const int r  = t >> 4;                         // staging pair row 0..15
    const int kc = (t & 15) << 3;                  // staging k-offset (floats)
    const int pr = pair0 + r;
    const unsigned wOff = (unsigned)r * 256 + (((unsigned)(2 * kc)) ^ ((unsigned)(r & 7) << 4));

    f32x4 acc[4];
    #pragma unroll
    for (int nf = 0; nf < 4; ++nf) acc[nf] = (f32x4){0.f, 0.f, 0.f, 0.f};

    const unsigned short* brow[4];
    #pragma unroll
    for (int nf = 0; nf < 4; ++nf)
        brow[nf] = Wm1t + (size_t)(64 * wid + 16 * nf + lr) * KTOT + 8 * lg;

    float4 va, vb;
    #define LOAD_A(s)                                                                  \
        {                                                                              \
            const float* src;                                                          \
            if ((s) == 0)                                                              \
                src = (kc < 64) ? hbuf + (size_t)pr * HDIM + kc                        \
                                : hbuf + (size_t)(B_PAIRS + pr) * HDIM + (kc - 64);    \
            else if ((s) <= 16)                                                        \
                src = fp1 + (size_t)pr * FPDIM + ((s) - 1) * 128 + kc;                 \
            else                                                                       \
                src = fp2 + (size_t)pr * FPDIM + ((s) - 17) * 128 + kc;                \
            va = ((const float4*)src)[0];                                              \
            vb = ((const float4*)src)[1];                                              \
        }
    #define STORE_A(base)                                                              \
        *(uint4*)((base) + wOff) = make_uint4(pack2(va.x, va.y), pack2(va.z, va.w),    \
                                              pack2(vb.x, vb.y), pack2(vb.z, vb.w));

    LOAD_A(0);
    STORE_A(lds);
    for (int s = 0; s < 33; ++s) {
        const bool more = (s + 1 < 33);
        if (more) LOAD_A(s + 1);                   // issue next-step globals early
        __syncthreads();                           // buf[s&1] ready; prev reads drained
        const unsigned char* buf = lds + (unsigned)((s & 1) << 12);
        const unsigned asw = (unsigned)(lr & 7) << 4;
        const int kglob = s << 7;
        #pragma unroll
        for (int ks = 0; ks < 4; ++ks) {
            const unsigned kb = (unsigned)(64 * ks + 16 * lg);
            const bf16x8 a = *(const bf16x8*)(buf + (unsigned)lr * 256 + (kb ^ asw));
            #pragma unroll
            for (int nf = 0; nf < 4; ++nf) {
                const bf16x8 bw = *(const bf16x8*)(brow[nf] + kglob + 32 * ks);
                acc[nf] = __builtin_amdgcn_mfma_f32_16x16x32_bf16(a, bw, acc[nf], 0, 0, 0);
            }
        }
        if (more) STORE_A(lds + (unsigned)(((s + 1) & 1) << 12));
    }

    // epilogue: bias, relu, dot Wm2, reduce over n, sigmoid
    float bm1v[4], wm2v[4];
    #pragma unroll
    for (int nf = 0; nf < 4; ++nf) {
        const int n = 64 * wid + 16 * nf + lr;
        bm1v[nf] = bm1[n];
        wm2v[nf] = Wm2[n];
    }
    #pragma unroll
    for (int reg = 0; reg < 4; ++reg) {            // row m = 4*lg + reg
        float p = 0.f;
        #pragma unroll
        for (int nf = 0; nf < 4; ++nf)
            p += fmaxf(acc[nf][reg] + bm1v[nf], 0.f) * wm2v[nf];
        p += __shfl_xor(p, 1, 64);
        p += __shfl_xor(p, 2, 64);
        p += __shfl_xor(p, 4, 64);
        p += __shfl_xor(p, 8, 64);
        if (lr == 0) pool[wid * 16 + 4 * lg + reg] = p;
    }
    __syncthreads();
    if (t < 16) {
        const float y = pool[t] + pool[16 + t] + pool[32 + t] + pool[48 + t] + bm2[0];
        out[pair0 + t] = 1.0f / (1.0f + expf(-y));
    }
    #undef LOAD_A
    #undef STORE_A
}

extern "C" void kernel_launch(void* const* d_in, const int* in_sizes, int n_in,
                              void* d_out, int out_size, void* d_ws, size_t ws_size,
                              hipStream_t stream) {
    const float* x1  = (const float*)d_in[0];
    const float* x2  = (const float*)d_in[1];
    const int*   e1  = (const int*)d_in[2];
    const int*   e2  = (const int*)d_in[3];
    const float* fp1 = (const float*)d_in[4];
    const float* fp2 = (const float*)d_in[5];
    const float* W1  = (const float*)d_in[6];
    const float* b1  = (const float*)d_in[7];
    const float* W2  = (const float*)d_in[8];
    const float* b2  = (const float*)d_in[9];
    const float* Wm1 = (const float*)d_in[10];
    const float* bm1 = (const float*)d_in[11];
    const float* Wm2 = (const float*)d_in[12];
    const float* bm2 = (const float*)d_in[13];
    float* out  = (float*)d_out;

    float* hbuf = (float*)d_ws;                                          // 2 MB
    unsigned short* W1t  = (unsigned short*)((char*)d_ws + (2 << 20));   // 16 KB
    unsigned short* W2t  = W1t + HDIM * FDIM;                            // 8 KB
    unsigned short* Wm1t = (unsigned short*)((char*)d_ws + (3 << 20));   // 2.16 MB

    hipLaunchKernelGGL(prep_weights, dim3(16), dim3(256), 0, stream, W1, W2, W1t, W2t);
    hipLaunchKernelGGL(prep_wm1, dim3(132, 8), dim3(256), 0, stream, Wm1, Wm1t);
    hipLaunchKernelGGL(encode_kernel, dim3(2 * B_PAIRS), dim3(64), 0, stream,
                       x1, x2, e1, e2, W1t, b1, W2t, b2, hbuf);
    hipLaunchKernelGGL(fused_mlp_kernel, dim3(B_PAIRS / 16), dim3(256), 0, stream,
                       fp1, fp2, hbuf, Wm1t, bm1, Wm2, bm2, out);
}